// Round 15
// baseline (234.186 us; speedup 1.0000x reference)
//
#include <hip/hip_runtime.h>
#include <math.h>

#define EPSV 1e-12f
#define BALLC (1.0f - 1e-6f)
#define MAXT 15.0f
#define NBM 1024     // moment-pass blocks (4 blocks/CU)
#define NBO 512      // k_out grid
#define BTO 512      // k_out block threads

// ws float offsets
#define MUF 0
#define PF 128
#define QF 256
#define SCF 384      // 16 scalars
#define OFFV 512
#define C_MM 0
#define C_PP 1
#define C_QQ 2
#define C_MP 3
#define C_MQ 4
#define C_PQ 5
#define C_TFM 6
#define C_LAMP 7
#define C_KS 8

typedef short bf16x8 __attribute__((ext_vector_type(8)));
typedef float f32x4 __attribute__((ext_vector_type(4)));

__device__ __forceinline__ float fast_tanh(float x) {
    float e = __expf(-2.f * x);
    return (1.f - e) / (1.f + e);
}
__device__ __forceinline__ float fast_atanh(float x) {
    return 0.5f * __logf((1.f + x) / (1.f - x));
}
__device__ __forceinline__ float qsum8(float v) {
    v += __shfl_xor(v, 1);
    v += __shfl_xor(v, 2);
    v += __shfl_xor(v, 4);
    return v;
}
__device__ __forceinline__ float wsum64(float v) {
    v += __shfl_xor(v, 1);
    v += __shfl_xor(v, 2);
    v += __shfl_xor(v, 4);
    v += __shfl_xor(v, 8);
    v += __shfl_xor(v, 16);
    v += __shfl_xor(v, 32);
    return v;
}
__device__ __forceinline__ unsigned cvt_pk_bf16(float lo, float hi) {
    unsigned r;
    asm volatile("v_cvt_pk_bf16_f32 %0, %1, %2" : "=v"(r) : "v"(lo), "v"(hi));
    return r;
}

// Taylor weights of logmap coefficients at (d=0, mm=0) given X2 = |x|^2.
__device__ __forceinline__ void taylor_weights(float X2, float* w) {
    float X2g = fmaxf(X2, 1e-8f);
    float r = __builtin_amdgcn_sqrtf(X2g);
    float rc = fminf(r, BALLC);
    float at0 = 0.5f * __logf((1.f + rc) * __builtin_amdgcn_rcpf(1.f - rc));
    float ir = __builtin_amdgcn_rcpf(r);
    float iX = ir * ir;
    float g0 = at0 * ir;
    float gd = (-1.f + at0 * (1.f - X2) * ir) * iX;
    float gm = ((1.f + X2) * 0.5f - at0 * (1.f - X2 * X2) * 0.5f * ir) * iX;
    float opx = 1.f + X2;
    w[0] = g0;
    w[1] = gd + 2.f * g0;
    w[2] = gm - (2.f + X2) * g0;
    w[3] = -g0 * opx;
    w[4] = -(gd * opx + 2.f * X2 * g0);
    w[5] = -gm * opx + g0 * opx * opx;
    w[6] = 4.f * at0 * at0;
    w[7] = -8.f * at0 * ir;
    w[8] = 4.f * at0 * opx * ir;
}

// ---------------------------------------------------------------------------
// One pass over x: vector/scalar moments (fp32) + M = sum w1*x x^T via MFMA.
// Double-buffered 32-row tiles: stage tile t+1 while MFMA consumes tile t;
// ONE barrier per tile. Staging buffers aliased by the final reduction
// scratch (LDS ~37KB -> 4 blocks/CU).
// ---------------------------------------------------------------------------
__global__ __launch_bounds__(1024) void k_moment(
        const float* __restrict__ x, float* __restrict__ vpartT,
        float* __restrict__ mpart, const int N, const int rpb, const int nbm) {
    __shared__ unsigned stash[2][2][2304];   // [buf][X=0/W=1][col*18 + kpair]
    __shared__ float ssc[16][4];
    const int tid = threadIdx.x;
    const int w = tid >> 6;
    const int l = tid & 63;
    const int bid = blockIdx.x;
    const int r0 = bid * rpb;
    const int r1 = (r0 + rpb < N) ? (r0 + rpb) : N;
    const int li = l & 15;
    const int g = l >> 4;
    const int I0 = (w >> 2) * 2;
    const int J0 = (w & 3) * 2;

    float2 aV00 = make_float2(0.f, 0.f), aV0m = make_float2(0.f, 0.f);
    float2 aAv = make_float2(0.f, 0.f), aDd = make_float2(0.f, 0.f);
    float sA00 = 0.f, sA0m = 0.f, sD0 = 0.f, sDm = 0.f;
    f32x4 accD[2][2];
#pragma unroll
    for (int a = 0; a < 2; ++a)
#pragma unroll
        for (int b = 0; b < 2; ++b) accD[a][b] = (f32x4){0.f, 0.f, 0.f, 0.f};

#define STAGE(BUF, TILE)                                                      \
    do {                                                                      \
        const int ra = r0 + (TILE) * 32 + 2 * w;                              \
        const int rb2 = ra + 1;                                               \
        float2 xa = make_float2(0.f, 0.f), xb2 = make_float2(0.f, 0.f);       \
        if (ra < r1) xa = *(const float2*)(x + (size_t)ra * 128 + 2 * l);     \
        if (rb2 < r1) xb2 = *(const float2*)(x + (size_t)rb2 * 128 + 2 * l);  \
        float X2a = wsum64(xa.x * xa.x + xa.y * xa.y);                        \
        float X2b = wsum64(xb2.x * xb2.x + xb2.y * xb2.y);                    \
        float wta[9], wtb[9];                                                 \
        if (ra < r1) {                                                        \
            taylor_weights(X2a, wta);                                         \
        } else {                                                              \
            _Pragma("unroll") for (int k = 0; k < 9; ++k) wta[k] = 0.f;       \
        }                                                                     \
        if (rb2 < r1) {                                                       \
            taylor_weights(X2b, wtb);                                         \
        } else {                                                              \
            _Pragma("unroll") for (int k = 0; k < 9; ++k) wtb[k] = 0.f;       \
        }                                                                     \
        aV00.x += wta[0] * xa.x + wtb[0] * xb2.x;                             \
        aV00.y += wta[0] * xa.y + wtb[0] * xb2.y;                             \
        aV0m.x += wta[2] * xa.x + wtb[2] * xb2.x;                             \
        aV0m.y += wta[2] * xa.y + wtb[2] * xb2.y;                             \
        aAv.x  += wta[4] * xa.x + wtb[4] * xb2.x;                             \
        aAv.y  += wta[4] * xa.y + wtb[4] * xb2.y;                             \
        aDd.x  += wta[7] * xa.x + wtb[7] * xb2.x;                             \
        aDd.y  += wta[7] * xa.y + wtb[7] * xb2.y;                             \
        sA00 += wta[3] + wtb[3];                                              \
        sA0m += wta[5] + wtb[5];                                              \
        sD0  += wta[6] + wtb[6];                                              \
        sDm  += wta[8] + wtb[8];                                              \
        unsigned* Xb = &stash[BUF][0][0];                                     \
        unsigned* Wb = &stash[BUF][1][0];                                     \
        Xb[(2 * l) * 18 + w]     = cvt_pk_bf16(xa.x, xb2.x);                  \
        Xb[(2 * l + 1) * 18 + w] = cvt_pk_bf16(xa.y, xb2.y);                  \
        Wb[(2 * l) * 18 + w]     = cvt_pk_bf16(wta[1] * xa.x, wtb[1] * xb2.x);\
        Wb[(2 * l + 1) * 18 + w] = cvt_pk_bf16(wta[1] * xa.y, wtb[1] * xb2.y);\
    } while (0)

#define MMSTEP(BUF)                                                           \
    do {                                                                      \
        const unsigned* Xb = &stash[BUF][0][0];                               \
        const unsigned* Wb = &stash[BUF][1][0];                               \
        union FU { uint2 d[2]; bf16x8 v; };                                   \
        bf16x8 af[2], bfr_[2];                                                \
        _Pragma("unroll")                                                     \
        for (int a = 0; a < 2; ++a) {                                         \
            int i = (I0 + a) * 16 + li;                                       \
            FU fa;                                                            \
            fa.d[0] = *(const uint2*)(Wb + i * 18 + 4 * g);                   \
            fa.d[1] = *(const uint2*)(Wb + i * 18 + 4 * g + 2);               \
            af[a] = fa.v;                                                     \
            int j = (J0 + a) * 16 + li;                                       \
            FU fb;                                                            \
            fb.d[0] = *(const uint2*)(Xb + j * 18 + 4 * g);                   \
            fb.d[1] = *(const uint2*)(Xb + j * 18 + 4 * g + 2);               \
            bfr_[a] = fb.v;                                                   \
        }                                                                     \
        _Pragma("unroll")                                                     \
        for (int a = 0; a < 2; ++a)                                           \
            _Pragma("unroll")                                                 \
            for (int b = 0; b < 2; ++b)                                       \
                accD[a][b] = __builtin_amdgcn_mfma_f32_16x16x32_bf16(         \
                    af[a], bfr_[b], accD[a][b], 0, 0, 0);                     \
    } while (0)

    const int nt = (r1 > r0) ? (r1 - r0 + 31) / 32 : 0;
    if (nt > 0) {
        STAGE(0, 0);
        __syncthreads();
        for (int t = 0; t < nt; ++t) {
            if (t + 1 < nt) STAGE((t + 1) & 1, t + 1);
            MMSTEP(t & 1);
            __syncthreads();
        }
    }
#undef STAGE
#undef MMSTEP

    // write M partial (C/D layout: col=lane&15, row=(lane>>4)*4+reg)
#pragma unroll
    for (int a = 0; a < 2; ++a)
#pragma unroll
        for (int b = 0; b < 2; ++b)
#pragma unroll
            for (int r = 0; r < 4; ++r) {
                int row = (I0 + a) * 16 + g * 4 + r;
                int col = (J0 + b) * 16 + li;
                mpart[(size_t)bid * 16384 + (size_t)row * 128 + col] = accD[a][b][r];
            }

    // final vector/scalar reduction: alias scratch onto the staging buffers
    float* rsm = (float*)&stash[0][0][0];   // 8192 floats <= 36864B
    rsm[(0 * 16 + w) * 128 + 2 * l] = aV00.x; rsm[(0 * 16 + w) * 128 + 2 * l + 1] = aV00.y;
    rsm[(1 * 16 + w) * 128 + 2 * l] = aV0m.x; rsm[(1 * 16 + w) * 128 + 2 * l + 1] = aV0m.y;
    rsm[(2 * 16 + w) * 128 + 2 * l] = aAv.x;  rsm[(2 * 16 + w) * 128 + 2 * l + 1] = aAv.y;
    rsm[(3 * 16 + w) * 128 + 2 * l] = aDd.x;  rsm[(3 * 16 + w) * 128 + 2 * l + 1] = aDd.y;
    if (l == 0) { ssc[w][0] = sA00; ssc[w][1] = sA0m; ssc[w][2] = sD0; ssc[w][3] = sDm; }
    __syncthreads();
    if (tid < 512) {
        int v = tid >> 7, c = tid & 127;
        float s = 0.f;
#pragma unroll
        for (int ww = 0; ww < 16; ++ww) s += rsm[(v * 16 + ww) * 128 + c];
        vpartT[(size_t)tid * nbm + bid] = s;
    }
    if (tid < 4) {
        float s = 0.f;
#pragma unroll
        for (int ww = 0; ww < 16; ++ww) s += ssc[ww][tid];
        vpartT[(size_t)(512 + tid) * nbm + bid] = s;
    }
}

__global__ __launch_bounds__(256) void k_redM(const float* __restrict__ mpart,
                                              float* __restrict__ mfin,
                                              const int nbm) {
    int e = blockIdx.x * 256 + threadIdx.x;
    float s = 0.f;
#pragma unroll 4
    for (int b = 0; b < nbm; ++b) s += mpart[(size_t)b * 16384 + e];
    mfin[e] = s;
}

__global__ __launch_bounds__(64) void k_redV(const float* __restrict__ vpartT,
                                             float* __restrict__ vfin,
                                             const int nbm) {
    int e = blockIdx.x;
    int l = threadIdx.x;
    float s = 0.f;
    for (int b = l; b < nbm; b += 64) s += vpartT[(size_t)e * nbm + b];
    s = wsum64(s);
    if (l == 0) vfin[e] = s;
}

__global__ __launch_bounds__(1024) void k_iter(
        const float* __restrict__ mpar, const float* __restrict__ vpar,
        float* __restrict__ ws, const float* __restrict__ vfin,
        const float* __restrict__ mfin, const float invN) {
    __shared__ float Msh[16384];
    __shared__ float varr[516];
    __shared__ float msum[128];
    __shared__ __align__(16) float lmu[128];
    __shared__ float lsc[2];
    const int tid = threadIdx.x;
    for (int e = tid; e < 16384; e += 1024) Msh[e] = mfin[e];
    if (tid < 516) varr[tid] = vfin[tid];
    if (tid < 128) { lmu[tid] = 0.f; msum[tid] = 0.f; }
    if (tid == 0) lsc[0] = 0.f;
    __syncthreads();

    const float* V00 = varr;
    const float* V0m = varr + 128;
    const float* Avec = varr + 256;
    const float* Dvec = varr + 384;

    for (int it = 0; it <= 15; ++it) {
        if (it > 0) {
            int i = tid >> 3, j8 = tid & 7;
            float p = 0.f;
#pragma unroll
            for (int jj = 0; jj < 16; ++jj) {
                int j = j8 + 8 * jj;
                p += Msh[i * 128 + j] * lmu[j];
            }
            p = qsum8(p);
            if (j8 == 0) msum[i] = p;
            __syncthreads();
        }
        if (tid < 64) {
            int c0 = 2 * tid, c1 = c0 + 1;
            float mm = lsc[0];
            float mu0 = lmu[c0], mu1 = lmu[c1];
            float dotA = wsum64(Avec[c0] * mu0 + Avec[c1] * mu1);
            float Sal = varr[512] + mm * varr[513] + dotA;
            float ms0 = (it > 0) ? msum[c0] : 0.f;
            float ms1 = (it > 0) ? msum[c1] : 0.f;
            float v0 = (V00[c0] + mm * V0m[c0] + ms0 + Sal * mu0) * invN;
            float v1 = (V00[c1] + mm * V0m[c1] + ms1 + Sal * mu1) * invN;
            float v2 = wsum64(v0 * v0 + v1 * v1);
            float nv = sqrtf(fmaxf(v2, EPSV));
            float lam = 2.f / fmaxf(1.f - mm, EPSV);
            float arg = fminf(lam * nv * 0.5f, MAXT);
            float tt = fast_tanh(arg);
            float sc = tt / nv;
            float sec0 = sc * v0, sec1 = sc * v1;
            float xy = wsum64(mu0 * sec0 + mu1 * sec1);
            float s2n = wsum64(sec0 * sec0 + sec1 * sec1);
            float A = 1.f + 2.f * xy + s2n;
            float B = 1.f - mm;
            float den = fmaxf(1.f + 2.f * xy + mm * s2n, EPSV);
            float idn = 1.f / den;
            float mun0 = (A * mu0 + B * sec0) * idn;
            float mun1 = (A * mu1 + B * sec1) * idn;
            float mm2 = wsum64(mun0 * mun0 + mun1 * mun1);
            lmu[c0] = mun0; lmu[c1] = mun1;
            if (tid == 0) lsc[0] = mm2;
        }
        __syncthreads();
    }

    if (tid < 64) {
        int c0 = 2 * tid, c1 = c0 + 1;
        float mm = lsc[0];
        float mu0 = lmu[c0], mu1 = lmu[c1];
        float dotD = wsum64(Dvec[c0] * mu0 + Dvec[c1] * mu1);
        float input_var = (varr[514] + mm * varr[515] + dotD) * invN;
        float mp0 = mpar[c0], mp1 = mpar[c1];
        float mpn2 = wsum64(mp0 * mp0 + mp1 * mp1);
        float pn = sqrtf(fmaxf(mpn2, EPSV));
        float th = fast_tanh(pn) / pn;
        float p0 = th * mp0, p1 = th * mp1;
        float pp = wsum64(p0 * p0 + p1 * p1);
        float pm = wsum64(p0 * mu0 + p1 * mu1);
        float A = 1.f - 2.f * pm + mm;
        float B = 1.f - pp;
        float den = fmaxf(1.f - 2.f * pm + pp * mm, EPSV);
        float q0 = (B * mu0 - A * p0) / den;
        float q1 = (B * mu1 - A * p1) / den;
        float qq = wsum64(q0 * q0 + q1 * q1);
        float mq = wsum64(mu0 * q0 + mu1 * q1);
        float pq = wsum64(p0 * q0 + p1 * q1);
        float tfm = fmaxf(1.f - mm, EPSV);
        float tfp = fmaxf(1.f - pp, EPSV);
        float lam_p = 2.f / tfp;
        float svar = sqrtf(vpar[0] / (input_var + 1e-6f));
        float ks = (tfp / tfm) * svar;
        ws[MUF + c0] = mu0; ws[MUF + c1] = mu1;
        ws[PF + c0] = p0;   ws[PF + c1] = p1;
        ws[QF + c0] = q0;   ws[QF + c1] = q1;
        if (tid == 0) {
            float* sc_ = ws + SCF;
            sc_[C_MM] = mm; sc_[C_PP] = pp; sc_[C_QQ] = qq; sc_[C_MP] = pm;
            sc_[C_MQ] = mq; sc_[C_PQ] = pq; sc_[C_TFM] = tfm;
            sc_[C_LAMP] = lam_p; sc_[C_KS] = ks;
        }
    }
}

__global__ __launch_bounds__(BTO) void k_out(const float* __restrict__ x,
                                             float* __restrict__ out,
                                             const float* __restrict__ ws,
                                             const int N, const int rpc) {
    const float* sc = ws + SCF;
    const float mm = sc[C_MM], pp = sc[C_PP], qq = sc[C_QQ];
    const float smp = sc[C_MP], smq = sc[C_MQ], spq = sc[C_PQ];
    const float tfm = sc[C_TFM], lam_p = sc[C_LAMP], ks = sc[C_KS];
    const int tid = threadIdx.x;
    const int lane = tid & 63;
    const int sub = lane & 7;
    const int grp = tid >> 3;
    const int bid = blockIdx.x;
    const float4* mu4 = (const float4*)(ws + MUF);
    const float4* p4 = (const float4*)(ws + PF);
    const float4* qv4 = (const float4*)(ws + QF);
    float4 mur[4], pr[4], qr[4];
#pragma unroll
    for (int k = 0; k < 4; ++k) {
        mur[k] = mu4[k * 8 + sub];
        pr[k] = p4[k * 8 + sub];
        qr[k] = qv4[k * 8 + sub];
    }
    const int chunk = (bid & 7) * (NBO / 8) + (bid >> 3);
    const int r0 = chunk * rpc;
    const int r1 = (r0 + rpc < N) ? (r0 + rpc) : N;
    for (int row = r0 + grp; row < r1; row += 64) {
        const float4* xr = (const float4*)(x + (size_t)row * 128);
        float4 xv[4];
#pragma unroll
        for (int k = 0; k < 4; ++k) xv[k] = xr[k * 8 + sub];
        float am = 0.f, ap = 0.f, aq = 0.f, an = 0.f;
#pragma unroll
        for (int k = 0; k < 4; ++k) {
            am += mur[k].x * xv[k].x + mur[k].y * xv[k].y + mur[k].z * xv[k].z + mur[k].w * xv[k].w;
            ap += pr[k].x * xv[k].x + pr[k].y * xv[k].y + pr[k].z * xv[k].z + pr[k].w * xv[k].w;
            aq += qr[k].x * xv[k].x + qr[k].y * xv[k].y + qr[k].z * xv[k].z + qr[k].w * xv[k].w;
            an += xv[k].x * xv[k].x + xv[k].y * xv[k].y + xv[k].z * xv[k].z + xv[k].w * xv[k].w;
        }
        float Dm = qsum8(am), Dp = qsum8(ap), Dq = qsum8(aq), X2 = qsum8(an);

        float A = 1.f - 2.f * Dm + X2;
        float B = 1.f - mm;
        float den = fmaxf(1.f - 2.f * Dm + mm * X2, EPSV);
        float iv = 1.f / den;
        float m_cm = -A * iv, m_cx = B * iv;
        float m_dm = (-A * mm + B * Dm) * iv;
        float m_dp = (-A * smp + B * Dp) * iv;
        float m_dq = (-A * smq + B * Dq) * iv;
        float m_n2 = (A * A * mm - 2.f * A * B * Dm + B * B * X2) * iv * iv;

        float n1 = sqrtf(fmaxf(m_n2, EPSV));
        float s1 = tfm * fast_atanh(fminf(n1, BALLC)) / n1;
        float t_cm = s1 * m_cm, t_cx = s1 * m_cx;
        float t_dm = s1 * m_dm, t_dp = s1 * m_dp, t_dq = s1 * m_dq;
        float t_n2 = s1 * s1 * m_n2;

        float xy = -t_dm, y2 = t_n2;
        A = 1.f + 2.f * xy + y2;
        B = 1.f - mm;
        den = fmaxf(1.f + 2.f * xy + mm * y2, EPSV);
        iv = 1.f / den;
        float w_cm = (-A + B * t_cm) * iv;
        float w_cx = B * t_cx * iv;
        float w_dp = (-A * smp + B * t_dp) * iv;
        float w_dq = (-A * smq + B * t_dq) * iv;
        float w_n2 = (A * A * mm + 2.f * A * B * xy + B * B * y2) * iv * iv;

        xy = w_dp; y2 = w_n2;
        A = 1.f + 2.f * xy + y2;
        B = 1.f - pp;
        den = fmaxf(1.f + 2.f * xy + pp * y2, EPSV);
        iv = 1.f / den;
        float w2_cm = B * w_cm * iv;
        float w2_cp = A * iv;
        float w2_cx = B * w_cx * iv;
        float w2_dp = (A * pp + B * w_dp) * iv;
        float w2_dq = (A * spq + B * w_dq) * iv;
        float w2_n2 = (A * A * pp + 2.f * A * B * xy + B * B * y2) * iv * iv;

        xy = w2_dq; y2 = w2_n2;
        A = 1.f + 2.f * xy + y2;
        B = 1.f - qq;
        den = fmaxf(1.f + 2.f * xy + qq * y2, EPSV);
        iv = 1.f / den;
        float w3_cm = B * w2_cm * iv;
        float w3_cp = B * w2_cp * iv;
        float w3_cq = A * iv;
        float w3_cx = B * w2_cx * iv;
        float w3_dp = (A * spq + B * w2_dp) * iv;
        float w3_n2 = (A * A * qq + 2.f * A * B * xy + B * B * y2) * iv * iv;

        float u_n2 = ks * ks * w3_n2;
        float nu = sqrtf(fmaxf(u_n2, EPSV));
        float arg = fminf(fmaxf(lam_p * nu * 0.5f, -MAXT), MAXT);
        float sf = fast_tanh(arg) * ks / nu;
        float s_cm = sf * w3_cm, s_cp = sf * w3_cp, s_cq = sf * w3_cq, s_cx = sf * w3_cx;
        float s_dp = sf * w3_dp;
        float s_n2 = sf * sf * w3_n2;

        xy = s_dp; y2 = s_n2;
        A = 1.f + 2.f * xy + y2;
        B = 1.f - pp;
        den = fmaxf(1.f + 2.f * xy + pp * y2, EPSV);
        iv = 1.f / den;
        float o_cm = B * s_cm * iv;
        float o_cp = (A + B * s_cp) * iv;
        float o_cq = B * s_cq * iv;
        float o_cx = B * s_cx * iv;

        float4* orow = (float4*)(out + (size_t)row * 128);
#pragma unroll
        for (int k = 0; k < 4; ++k) {
            float4 mk = mur[k], pk = pr[k], qk = qr[k], xk = xv[k];
            float4 ov;
            ov.x = o_cm * mk.x + o_cp * pk.x + o_cq * qk.x + o_cx * xk.x;
            ov.y = o_cm * mk.y + o_cp * pk.y + o_cq * qk.y + o_cx * xk.y;
            ov.z = o_cm * mk.z + o_cp * pk.z + o_cq * qk.z + o_cx * xk.z;
            ov.w = o_cm * mk.w + o_cp * pk.w + o_cq * qk.w + o_cx * xk.w;
            orow[k * 8 + sub] = ov;
        }
    }
}

extern "C" void kernel_launch(void* const* d_in, const int* in_sizes, int n_in,
                              void* d_out, int out_size, void* d_ws, size_t ws_size,
                              hipStream_t stream) {
    const float* x = (const float*)d_in[0];
    const float* mpar = (const float*)d_in[1];
    const float* vpar = (const float*)d_in[2];
    float* out = (float*)d_out;
    float* ws = (float*)d_ws;
    int N = in_sizes[0] / 128;
    float invN = 1.f / (float)N;

    long wsf = (long)(ws_size / sizeof(float));
    int nbm = NBM;
    long need = OFFV + (long)nbm * 520 + 520 + 16384 + (long)nbm * 16384;
    if (wsf < need) {
        long nb = (wsf - OFFV - 520 - 16384) / 16904;
        nbm = (nb < 8) ? 8 : (int)nb;
        if (nbm > NBM) nbm = NBM;
    }
    int rpb = (N + nbm - 1) / nbm;
    int rpo = (N + NBO - 1) / NBO;
    float* vpartT = ws + OFFV;
    float* vfin = vpartT + (long)nbm * 520;
    float* mfin = vfin + 520;
    float* mpart = mfin + 16384;

    hipLaunchKernelGGL(k_moment, dim3(nbm), dim3(1024), 0, stream,
                       x, vpartT, mpart, N, rpb, nbm);
    hipLaunchKernelGGL(k_redM, dim3(64), dim3(256), 0, stream, mpart, mfin, nbm);
    hipLaunchKernelGGL(k_redV, dim3(516), dim3(64), 0, stream, vpartT, vfin, nbm);
    hipLaunchKernelGGL(k_iter, dim3(1), dim3(1024), 0, stream,
                       mpar, vpar, ws, vfin, mfin, invN);
    hipLaunchKernelGGL(k_out, dim3(NBO), dim3(BTO), 0, stream, x, out, ws, N, rpo);
}

// Round 16
// 185.175 us; speedup vs baseline: 1.2647x; 1.2647x over previous
//
#include <hip/hip_runtime.h>
#include <math.h>

#define EPSV 1e-12f
#define BALLC (1.0f - 1e-6f)
#define MAXT 15.0f
#define NBM 512      // moment-pass blocks
#define NBO 512      // k_out grid
#define BTO 512      // k_out block threads

// ws float offsets
#define MUF 0
#define PF 128
#define QF 256
#define SCF 384      // 16 scalars
#define OFFV 512
#define C_MM 0
#define C_PP 1
#define C_QQ 2
#define C_MP 3
#define C_MQ 4
#define C_PQ 5
#define C_TFM 6
#define C_LAMP 7
#define C_KS 8

typedef short bf16x8 __attribute__((ext_vector_type(8)));
typedef float f32x4 __attribute__((ext_vector_type(4)));

__device__ __forceinline__ float fast_tanh(float x) {
    float e = __expf(-2.f * x);
    return (1.f - e) / (1.f + e);
}
__device__ __forceinline__ float fast_atanh(float x) {
    return 0.5f * __logf((1.f + x) / (1.f - x));
}
__device__ __forceinline__ float qsum8(float v) {
    v += __shfl_xor(v, 1);
    v += __shfl_xor(v, 2);
    v += __shfl_xor(v, 4);
    return v;
}
__device__ __forceinline__ float wsum64(float v) {
    v += __shfl_xor(v, 1);
    v += __shfl_xor(v, 2);
    v += __shfl_xor(v, 4);
    v += __shfl_xor(v, 8);
    v += __shfl_xor(v, 16);
    v += __shfl_xor(v, 32);
    return v;
}
__device__ __forceinline__ unsigned cvt_pk_bf16(float lo, float hi) {
    unsigned r;
    asm volatile("v_cvt_pk_bf16_f32 %0, %1, %2" : "=v"(r) : "v"(lo), "v"(hi));
    return r;
}

// Taylor weights of logmap coefficients at (d=0, mm=0) given X2 = |x|^2.
// delta ~ w0 + w1*d + w2*mm ; alpha ~ w3 + w4*d + w5*mm ; dist^2 ~ w6 + w7*d + w8*mm.
__device__ __forceinline__ void taylor_weights(float X2, float* w) {
    float X2g = fmaxf(X2, 1e-8f);
    float r = __builtin_amdgcn_sqrtf(X2g);
    float rc = fminf(r, BALLC);
    float at0 = 0.5f * __logf((1.f + rc) * __builtin_amdgcn_rcpf(1.f - rc));
    float ir = __builtin_amdgcn_rcpf(r);
    float iX = ir * ir;
    float g0 = at0 * ir;
    float gd = (-1.f + at0 * (1.f - X2) * ir) * iX;
    float gm = ((1.f + X2) * 0.5f - at0 * (1.f - X2 * X2) * 0.5f * ir) * iX;
    float opx = 1.f + X2;
    w[0] = g0;
    w[1] = gd + 2.f * g0;
    w[2] = gm - (2.f + X2) * g0;
    w[3] = -g0 * opx;
    w[4] = -(gd * opx + 2.f * X2 * g0);
    w[5] = -gm * opx + g0 * opx * opx;
    w[6] = 4.f * at0 * at0;
    w[7] = -8.f * at0 * ir;
    w[8] = 4.f * at0 * opx * ir;
}

// ---------------------------------------------------------------------------
// One pass over x: vector/scalar moments (fp32) + M = sum w1*x x^T via MFMA.
// Row-pair staging: wave w owns rows (2w, 2w+1); LDS holds u32-packed bf16
// pairs {row 2r lo, row 2r+1 hi} at [col][kpair] stride 18 u32 (8B-aligned
// b64 fragment reads). k-map identical for A and B fragments.
// ---------------------------------------------------------------------------
__global__ __launch_bounds__(1024) void k_moment(
        const float* __restrict__ x, float* __restrict__ vpartT,
        float* __restrict__ mpart, const int N, const int rpb, const int nbm) {
    __shared__ unsigned Xt[128 * 18];
    __shared__ unsigned Wt[128 * 18];
    __shared__ float rsm[8192];
    __shared__ float ssc[16][4];
    const int tid = threadIdx.x;
    const int w = tid >> 6;
    const int l = tid & 63;
    const int bid = blockIdx.x;
    const int r0 = bid * rpb;
    const int r1 = (r0 + rpb < N) ? (r0 + rpb) : N;
    const int li = l & 15;
    const int g = l >> 4;
    const int I0 = (w >> 2) * 2;
    const int J0 = (w & 3) * 2;

    float2 aV00 = make_float2(0.f, 0.f), aV0m = make_float2(0.f, 0.f);
    float2 aAv = make_float2(0.f, 0.f), aDd = make_float2(0.f, 0.f);
    float sA00 = 0.f, sA0m = 0.f, sD0 = 0.f, sDm = 0.f;
    f32x4 accD[2][2];
#pragma unroll
    for (int a = 0; a < 2; ++a)
#pragma unroll
        for (int b = 0; b < 2; ++b) accD[a][b] = (f32x4){0.f, 0.f, 0.f, 0.f};

    for (int rb = r0; rb < r1; rb += 32) {
        const int ra = rb + 2 * w;        // wave-uniform row pair
        const int rbn = ra + 1;
        float2 xa = make_float2(0.f, 0.f), xb = make_float2(0.f, 0.f);
        if (ra < r1) xa = *(const float2*)(x + (size_t)ra * 128 + 2 * l);
        if (rbn < r1) xb = *(const float2*)(x + (size_t)rbn * 128 + 2 * l);
        float X2a = wsum64(xa.x * xa.x + xa.y * xa.y);
        float X2b = wsum64(xb.x * xb.x + xb.y * xb.y);
        float wta[9], wtb[9];
        if (ra < r1) {
            taylor_weights(X2a, wta);
        } else {
#pragma unroll
            for (int k = 0; k < 9; ++k) wta[k] = 0.f;
        }
        if (rbn < r1) {
            taylor_weights(X2b, wtb);
        } else {
#pragma unroll
            for (int k = 0; k < 9; ++k) wtb[k] = 0.f;
        }
        aV00.x += wta[0] * xa.x + wtb[0] * xb.x;
        aV00.y += wta[0] * xa.y + wtb[0] * xb.y;
        aV0m.x += wta[2] * xa.x + wtb[2] * xb.x;
        aV0m.y += wta[2] * xa.y + wtb[2] * xb.y;
        aAv.x  += wta[4] * xa.x + wtb[4] * xb.x;
        aAv.y  += wta[4] * xa.y + wtb[4] * xb.y;
        aDd.x  += wta[7] * xa.x + wtb[7] * xb.x;
        aDd.y  += wta[7] * xa.y + wtb[7] * xb.y;
        sA00 += wta[3] + wtb[3];
        sA0m += wta[5] + wtb[5];
        sD0  += wta[6] + wtb[6];
        sDm  += wta[8] + wtb[8];
        Xt[(2 * l) * 18 + w]     = cvt_pk_bf16(xa.x, xb.x);
        Xt[(2 * l + 1) * 18 + w] = cvt_pk_bf16(xa.y, xb.y);
        Wt[(2 * l) * 18 + w]     = cvt_pk_bf16(wta[1] * xa.x, wtb[1] * xb.x);
        Wt[(2 * l + 1) * 18 + w] = cvt_pk_bf16(wta[1] * xa.y, wtb[1] * xb.y);
        __syncthreads();
        union FU { uint2 d[2]; bf16x8 v; };
        bf16x8 af[2], bfr_[2];
#pragma unroll
        for (int a = 0; a < 2; ++a) {
            int i = (I0 + a) * 16 + li;
            FU fa;
            fa.d[0] = *(const uint2*)(Wt + i * 18 + 4 * g);
            fa.d[1] = *(const uint2*)(Wt + i * 18 + 4 * g + 2);
            af[a] = fa.v;
            int j = (J0 + a) * 16 + li;
            FU fb;
            fb.d[0] = *(const uint2*)(Xt + j * 18 + 4 * g);
            fb.d[1] = *(const uint2*)(Xt + j * 18 + 4 * g + 2);
            bfr_[a] = fb.v;
        }
#pragma unroll
        for (int a = 0; a < 2; ++a)
#pragma unroll
            for (int b = 0; b < 2; ++b)
                accD[a][b] = __builtin_amdgcn_mfma_f32_16x16x32_bf16(
                    af[a], bfr_[b], accD[a][b], 0, 0, 0);
        __syncthreads();
    }

#pragma unroll
    for (int a = 0; a < 2; ++a)
#pragma unroll
        for (int b = 0; b < 2; ++b)
#pragma unroll
            for (int r = 0; r < 4; ++r) {
                int row = (I0 + a) * 16 + g * 4 + r;
                int col = (J0 + b) * 16 + li;
                mpart[(size_t)bid * 16384 + (size_t)row * 128 + col] = accD[a][b][r];
            }

    rsm[(0 * 16 + w) * 128 + 2 * l] = aV00.x; rsm[(0 * 16 + w) * 128 + 2 * l + 1] = aV00.y;
    rsm[(1 * 16 + w) * 128 + 2 * l] = aV0m.x; rsm[(1 * 16 + w) * 128 + 2 * l + 1] = aV0m.y;
    rsm[(2 * 16 + w) * 128 + 2 * l] = aAv.x;  rsm[(2 * 16 + w) * 128 + 2 * l + 1] = aAv.y;
    rsm[(3 * 16 + w) * 128 + 2 * l] = aDd.x;  rsm[(3 * 16 + w) * 128 + 2 * l + 1] = aDd.y;
    if (l == 0) { ssc[w][0] = sA00; ssc[w][1] = sA0m; ssc[w][2] = sD0; ssc[w][3] = sDm; }
    __syncthreads();
    if (tid < 512) {
        int v = tid >> 7, c = tid & 127;
        float s = 0.f;
#pragma unroll
        for (int ww = 0; ww < 16; ++ww) s += rsm[(v * 16 + ww) * 128 + c];
        vpartT[(size_t)tid * nbm + bid] = s;
    }
    if (tid < 4) {
        float s = 0.f;
#pragma unroll
        for (int ww = 0; ww < 16; ++ww) s += ssc[ww][tid];
        vpartT[(size_t)(512 + tid) * nbm + bid] = s;
    }
}

__global__ __launch_bounds__(256) void k_redM(const float* __restrict__ mpart,
                                              float* __restrict__ mfin,
                                              const int nbm) {
    int e = blockIdx.x * 256 + threadIdx.x;
    float s = 0.f;
#pragma unroll 4
    for (int b = 0; b < nbm; ++b) s += mpart[(size_t)b * 16384 + e];
    mfin[e] = s;
}

__global__ __launch_bounds__(64) void k_redV(const float* __restrict__ vpartT,
                                             float* __restrict__ vfin,
                                             const int nbm) {
    int e = blockIdx.x;
    int l = threadIdx.x;
    float s = 0.f;
    for (int b = l; b < nbm; b += 64) s += vpartT[(size_t)e * nbm + b];
    s = wsum64(s);
    if (l == 0) vfin[e] = s;
}

__global__ __launch_bounds__(1024) void k_iter(
        const float* __restrict__ mpar, const float* __restrict__ vpar,
        float* __restrict__ ws, const float* __restrict__ vfin,
        const float* __restrict__ mfin, const float invN) {
    __shared__ float Msh[16384];
    __shared__ float varr[516];
    __shared__ float msum[128];
    __shared__ __align__(16) float lmu[128];
    __shared__ float lsc[2];
    const int tid = threadIdx.x;
    for (int e = tid; e < 16384; e += 1024) Msh[e] = mfin[e];
    if (tid < 516) varr[tid] = vfin[tid];
    if (tid < 128) { lmu[tid] = 0.f; msum[tid] = 0.f; }
    if (tid == 0) lsc[0] = 0.f;
    __syncthreads();

    const float* V00 = varr;
    const float* V0m = varr + 128;
    const float* Avec = varr + 256;
    const float* Dvec = varr + 384;

    for (int it = 0; it <= 15; ++it) {
        if (it > 0) {
            int i = tid >> 3, j8 = tid & 7;
            float p = 0.f;
#pragma unroll
            for (int jj = 0; jj < 16; ++jj) {
                int j = j8 + 8 * jj;
                p += Msh[i * 128 + j] * lmu[j];
            }
            p = qsum8(p);
            if (j8 == 0) msum[i] = p;
            __syncthreads();
        }
        if (tid < 64) {
            int c0 = 2 * tid, c1 = c0 + 1;
            float mm = lsc[0];
            float mu0 = lmu[c0], mu1 = lmu[c1];
            float dotA = wsum64(Avec[c0] * mu0 + Avec[c1] * mu1);
            float Sal = varr[512] + mm * varr[513] + dotA;
            float ms0 = (it > 0) ? msum[c0] : 0.f;
            float ms1 = (it > 0) ? msum[c1] : 0.f;
            float v0 = (V00[c0] + mm * V0m[c0] + ms0 + Sal * mu0) * invN;
            float v1 = (V00[c1] + mm * V0m[c1] + ms1 + Sal * mu1) * invN;
            float v2 = wsum64(v0 * v0 + v1 * v1);
            float nv = sqrtf(fmaxf(v2, EPSV));
            float lam = 2.f / fmaxf(1.f - mm, EPSV);
            float arg = fminf(lam * nv * 0.5f, MAXT);
            float tt = fast_tanh(arg);
            float sc = tt / nv;
            float sec0 = sc * v0, sec1 = sc * v1;
            float xy = wsum64(mu0 * sec0 + mu1 * sec1);
            float s2n = wsum64(sec0 * sec0 + sec1 * sec1);
            float A = 1.f + 2.f * xy + s2n;
            float B = 1.f - mm;
            float den = fmaxf(1.f + 2.f * xy + mm * s2n, EPSV);
            float idn = 1.f / den;
            float mun0 = (A * mu0 + B * sec0) * idn;
            float mun1 = (A * mu1 + B * sec1) * idn;
            float mm2 = wsum64(mun0 * mun0 + mun1 * mun1);
            lmu[c0] = mun0; lmu[c1] = mun1;
            if (tid == 0) lsc[0] = mm2;
        }
        __syncthreads();
    }

    if (tid < 64) {
        int c0 = 2 * tid, c1 = c0 + 1;
        float mm = lsc[0];
        float mu0 = lmu[c0], mu1 = lmu[c1];
        float dotD = wsum64(Dvec[c0] * mu0 + Dvec[c1] * mu1);
        float input_var = (varr[514] + mm * varr[515] + dotD) * invN;
        float mp0 = mpar[c0], mp1 = mpar[c1];
        float mpn2 = wsum64(mp0 * mp0 + mp1 * mp1);
        float pn = sqrtf(fmaxf(mpn2, EPSV));
        float th = fast_tanh(pn) / pn;
        float p0 = th * mp0, p1 = th * mp1;
        float pp = wsum64(p0 * p0 + p1 * p1);
        float pm = wsum64(p0 * mu0 + p1 * mu1);
        float A = 1.f - 2.f * pm + mm;
        float B = 1.f - pp;
        float den = fmaxf(1.f - 2.f * pm + pp * mm, EPSV);
        float q0 = (B * mu0 - A * p0) / den;
        float q1 = (B * mu1 - A * p1) / den;
        float qq = wsum64(q0 * q0 + q1 * q1);
        float mq = wsum64(mu0 * q0 + mu1 * q1);
        float pq = wsum64(p0 * q0 + p1 * q1);
        float tfm = fmaxf(1.f - mm, EPSV);
        float tfp = fmaxf(1.f - pp, EPSV);
        float lam_p = 2.f / tfp;
        float svar = sqrtf(vpar[0] / (input_var + 1e-6f));
        float ks = (tfp / tfm) * svar;
        ws[MUF + c0] = mu0; ws[MUF + c1] = mu1;
        ws[PF + c0] = p0;   ws[PF + c1] = p1;
        ws[QF + c0] = q0;   ws[QF + c1] = q1;
        if (tid == 0) {
            float* sc_ = ws + SCF;
            sc_[C_MM] = mm; sc_[C_PP] = pp; sc_[C_QQ] = qq; sc_[C_MP] = pm;
            sc_[C_MQ] = mq; sc_[C_PQ] = pq; sc_[C_TFM] = tfm;
            sc_[C_LAMP] = lam_p; sc_[C_KS] = ks;
        }
    }
}

__global__ __launch_bounds__(BTO) void k_out(const float* __restrict__ x,
                                             float* __restrict__ out,
                                             const float* __restrict__ ws,
                                             const int N, const int rpc) {
    const float* sc = ws + SCF;
    const float mm = sc[C_MM], pp = sc[C_PP], qq = sc[C_QQ];
    const float smp = sc[C_MP], smq = sc[C_MQ], spq = sc[C_PQ];
    const float tfm = sc[C_TFM], lam_p = sc[C_LAMP], ks = sc[C_KS];
    const int tid = threadIdx.x;
    const int lane = tid & 63;
    const int sub = lane & 7;
    const int grp = tid >> 3;
    const int bid = blockIdx.x;
    const float4* mu4 = (const float4*)(ws + MUF);
    const float4* p4 = (const float4*)(ws + PF);
    const float4* qv4 = (const float4*)(ws + QF);
    float4 mur[4], pr[4], qr[4];
#pragma unroll
    for (int k = 0; k < 4; ++k) {
        mur[k] = mu4[k * 8 + sub];
        pr[k] = p4[k * 8 + sub];
        qr[k] = qv4[k * 8 + sub];
    }
    const int chunk = (bid & 7) * (NBO / 8) + (bid >> 3);
    const int r0 = chunk * rpc;
    const int r1 = (r0 + rpc < N) ? (r0 + rpc) : N;
    for (int row = r0 + grp; row < r1; row += 64) {
        const float4* xr = (const float4*)(x + (size_t)row * 128);
        float4 xv[4];
#pragma unroll
        for (int k = 0; k < 4; ++k) xv[k] = xr[k * 8 + sub];
        float am = 0.f, ap = 0.f, aq = 0.f, an = 0.f;
#pragma unroll
        for (int k = 0; k < 4; ++k) {
            am += mur[k].x * xv[k].x + mur[k].y * xv[k].y + mur[k].z * xv[k].z + mur[k].w * xv[k].w;
            ap += pr[k].x * xv[k].x + pr[k].y * xv[k].y + pr[k].z * xv[k].z + pr[k].w * xv[k].w;
            aq += qr[k].x * xv[k].x + qr[k].y * xv[k].y + qr[k].z * xv[k].z + qr[k].w * xv[k].w;
            an += xv[k].x * xv[k].x + xv[k].y * xv[k].y + xv[k].z * xv[k].z + xv[k].w * xv[k].w;
        }
        float Dm = qsum8(am), Dp = qsum8(ap), Dq = qsum8(aq), X2 = qsum8(an);

        float A = 1.f - 2.f * Dm + X2;
        float B = 1.f - mm;
        float den = fmaxf(1.f - 2.f * Dm + mm * X2, EPSV);
        float iv = 1.f / den;
        float m_cm = -A * iv, m_cx = B * iv;
        float m_dm = (-A * mm + B * Dm) * iv;
        float m_dp = (-A * smp + B * Dp) * iv;
        float m_dq = (-A * smq + B * Dq) * iv;
        float m_n2 = (A * A * mm - 2.f * A * B * Dm + B * B * X2) * iv * iv;

        float n1 = sqrtf(fmaxf(m_n2, EPSV));
        float s1 = tfm * fast_atanh(fminf(n1, BALLC)) / n1;
        float t_cm = s1 * m_cm, t_cx = s1 * m_cx;
        float t_dm = s1 * m_dm, t_dp = s1 * m_dp, t_dq = s1 * m_dq;
        float t_n2 = s1 * s1 * m_n2;

        float xy = -t_dm, y2 = t_n2;
        A = 1.f + 2.f * xy + y2;
        B = 1.f - mm;
        den = fmaxf(1.f + 2.f * xy + mm * y2, EPSV);
        iv = 1.f / den;
        float w_cm = (-A + B * t_cm) * iv;
        float w_cx = B * t_cx * iv;
        float w_dp = (-A * smp + B * t_dp) * iv;
        float w_dq = (-A * smq + B * t_dq) * iv;
        float w_n2 = (A * A * mm + 2.f * A * B * xy + B * B * y2) * iv * iv;

        xy = w_dp; y2 = w_n2;
        A = 1.f + 2.f * xy + y2;
        B = 1.f - pp;
        den = fmaxf(1.f + 2.f * xy + pp * y2, EPSV);
        iv = 1.f / den;
        float w2_cm = B * w_cm * iv;
        float w2_cp = A * iv;
        float w2_cx = B * w_cx * iv;
        float w2_dp = (A * pp + B * w_dp) * iv;
        float w2_dq = (A * spq + B * w_dq) * iv;
        float w2_n2 = (A * A * pp + 2.f * A * B * xy + B * B * y2) * iv * iv;

        xy = w2_dq; y2 = w2_n2;
        A = 1.f + 2.f * xy + y2;
        B = 1.f - qq;
        den = fmaxf(1.f + 2.f * xy + qq * y2, EPSV);
        iv = 1.f / den;
        float w3_cm = B * w2_cm * iv;
        float w3_cp = B * w2_cp * iv;
        float w3_cq = A * iv;
        float w3_cx = B * w2_cx * iv;
        float w3_dp = (A * spq + B * w2_dp) * iv;
        float w3_n2 = (A * A * qq + 2.f * A * B * xy + B * B * y2) * iv * iv;

        float u_n2 = ks * ks * w3_n2;
        float nu = sqrtf(fmaxf(u_n2, EPSV));
        float arg = fminf(fmaxf(lam_p * nu * 0.5f, -MAXT), MAXT);
        float sf = fast_tanh(arg) * ks / nu;
        float s_cm = sf * w3_cm, s_cp = sf * w3_cp, s_cq = sf * w3_cq, s_cx = sf * w3_cx;
        float s_dp = sf * w3_dp;
        float s_n2 = sf * sf * w3_n2;

        xy = s_dp; y2 = s_n2;
        A = 1.f + 2.f * xy + y2;
        B = 1.f - pp;
        den = fmaxf(1.f + 2.f * xy + pp * y2, EPSV);
        iv = 1.f / den;
        float o_cm = B * s_cm * iv;
        float o_cp = (A + B * s_cp) * iv;
        float o_cq = B * s_cq * iv;
        float o_cx = B * s_cx * iv;

        float4* orow = (float4*)(out + (size_t)row * 128);
#pragma unroll
        for (int k = 0; k < 4; ++k) {
            float4 mk = mur[k], pk = pr[k], qk = qr[k], xk = xv[k];
            float4 ov;
            ov.x = o_cm * mk.x + o_cp * pk.x + o_cq * qk.x + o_cx * xk.x;
            ov.y = o_cm * mk.y + o_cp * pk.y + o_cq * qk.y + o_cx * xk.y;
            ov.z = o_cm * mk.z + o_cp * pk.z + o_cq * qk.z + o_cx * xk.z;
            ov.w = o_cm * mk.w + o_cp * pk.w + o_cq * qk.w + o_cx * xk.w;
            orow[k * 8 + sub] = ov;
        }
    }
}

extern "C" void kernel_launch(void* const* d_in, const int* in_sizes, int n_in,
                              void* d_out, int out_size, void* d_ws, size_t ws_size,
                              hipStream_t stream) {
    const float* x = (const float*)d_in[0];
    const float* mpar = (const float*)d_in[1];
    const float* vpar = (const float*)d_in[2];
    float* out = (float*)d_out;
    float* ws = (float*)d_ws;
    int N = in_sizes[0] / 128;
    float invN = 1.f / (float)N;

    long wsf = (long)(ws_size / sizeof(float));
    int nbm = NBM;
    long need = OFFV + (long)nbm * 520 + 520 + 16384 + (long)nbm * 16384;
    if (wsf < need) {
        long nb = (wsf - OFFV - 520 - 16384) / 16904;
        nbm = (nb < 8) ? 8 : (int)nb;
        if (nbm > NBM) nbm = NBM;
    }
    int rpb = (N + nbm - 1) / nbm;
    int rpo = (N + NBO - 1) / NBO;
    float* vpartT = ws + OFFV;
    float* vfin = vpartT + (long)nbm * 520;
    float* mfin = vfin + 520;
    float* mpart = mfin + 16384;

    hipLaunchKernelGGL(k_moment, dim3(nbm), dim3(1024), 0, stream,
                       x, vpartT, mpart, N, rpb, nbm);
    hipLaunchKernelGGL(k_redM, dim3(64), dim3(256), 0, stream, mpart, mfin, nbm);
    hipLaunchKernelGGL(k_redV, dim3(516), dim3(64), 0, stream, vpartT, vfin, nbm);
    hipLaunchKernelGGL(k_iter, dim3(1), dim3(1024), 0, stream,
                       mpar, vpar, ws, vfin, mfin, invN);
    hipLaunchKernelGGL(k_out, dim3(NBO), dim3(BTO), 0, stream, x, out, ws, N, rpo);
}